// Round 12
// baseline (131.914 us; speedup 1.0000x reference)
//
#include <hip/hip_runtime.h>

#define EPB 32          // envs per block (16 per wave, 4 lanes per env)
#define BLOCK 128       // 2 waves per block; 1 wave/SIMD at 2 blocks/CU
#define HS 292          // H LDS stride (288 + 4)
#define GS 148          // G/Ginv LDS stride (144 + 4)
#define SS 28           // b / aux stride (24 + 4)

#define WFENCE() __builtin_amdgcn_wave_barrier()   // compiler fence, 0 instr

#define DPP_XOR1 0xB1   // quad_perm [1,0,3,2]  : lane ^= 1
#define DPP_XOR2 0x4E   // quad_perm [2,3,0,1]  : lane ^= 2
#define DPP_QP3  0x1B   // quad_perm [3,2,1,0]  : lane ^= 3

typedef float f2 __attribute__((ext_vector_type(2)));

__device__ __forceinline__ f2 pkfma(f2 a, f2 b, f2 c) {
  return __builtin_elementwise_fma(a, b, c);   // -> v_pk_fma_f32 on gfx950
}

// acc += dot(f4, s4)
#define FMA4(acc, f, s)                                         \
  acc = fmaf((f).x, (s).x,                                      \
        fmaf((f).y, (s).y,                                      \
        fmaf((f).z, (s).z,                                      \
        fmaf((f).w, (s).w, (acc)))))

// acc4 += s * v4
#define VFMA(acc, s, v)                                         \
  { (acc).x = fmaf((s), (v).x, (acc).x);                        \
    (acc).y = fmaf((s), (v).y, (acc).y);                        \
    (acc).z = fmaf((s), (v).z, (acc).z);                        \
    (acc).w = fmaf((s), (v).w, (acc).w); }

#define ADD4(A, B) { (A).x += (B).x; (A).y += (B).y; (A).z += (B).z; (A).w += (B).w; }

template<int CTRL>
__device__ __forceinline__ float dppv(float v) {
  return __int_as_float(__builtin_amdgcn_update_dpp(
      0, __float_as_int(v), CTRL, 0xF, 0xF, true));
}

template<int K>
__device__ __forceinline__ float getel(const float4& a, const float4& b, const float4& c) {
  if constexpr (K == 0) return a.x; else if constexpr (K == 1) return a.y;
  else if constexpr (K == 2) return a.z; else if constexpr (K == 3) return a.w;
  else if constexpr (K == 4) return b.x; else if constexpr (K == 5) return b.y;
  else if constexpr (K == 6) return b.z; else if constexpr (K == 7) return b.w;
  else if constexpr (K == 8) return c.x; else if constexpr (K == 9) return c.y;
  else if constexpr (K == 10) return c.z; else return c.w;
}
template<int K>
__device__ __forceinline__ void setel(float4& a, float4& b, float4& c, float v) {
  if constexpr (K == 0) a.x = v; else if constexpr (K == 1) a.y = v;
  else if constexpr (K == 2) a.z = v; else if constexpr (K == 3) a.w = v;
  else if constexpr (K == 4) b.x = v; else if constexpr (K == 5) b.y = v;
  else if constexpr (K == 6) b.z = v; else if constexpr (K == 7) b.w = v;
  else if constexpr (K == 8) c.x = v; else if constexpr (K == 9) c.y = v;
  else if constexpr (K == 10) c.z = v; else c.w = v;
}

__device__ __forceinline__ float dot12(float4 a0, float4 a1, float4 a2,
                                       const float* p) {
  const float4* p4 = (const float4*)p;
  float4 b0 = p4[0], b1 = p4[1], b2 = p4[2];
  float acc = 0.f;
  FMA4(acc, a0, b0); FMA4(acc, a1, b1); FMA4(acc, a2, b2);
  return acc;
}

// ---- register-resident Gauss-Jordan, 3 row-sets per lane ------------------
// Lane t (0..3) owns rows t (set0), t+4 (set1), t+8 (set2).
// Pivot row goes through LDS (round-10 proven: cheaper than DPP-broadcast —
// r11's DPP variant added ~600 issue-slots and regressed 9%).
template<int K>
__device__ __forceinline__ void pivot_pub(float4& a, float4& b, float4& c, float* piv) {
  float ip = 1.0f / getel<K>(a, b, c);
  setel<K>(a, b, c, 1.0f);
  a.x *= ip; a.y *= ip; a.z *= ip; a.w *= ip;
  b.x *= ip; b.y *= ip; b.z *= ip; b.w *= ip;
  c.x *= ip; c.y *= ip; c.z *= ip; c.w *= ip;
  float4* pv = (float4*)piv;
  pv[0] = a; pv[1] = b; pv[2] = c;
}

#define ELIM(f, A, B, C)                                              \
  { (A).x = fmaf(-(f), p0.x, (A).x); (A).y = fmaf(-(f), p0.y, (A).y); \
    (A).z = fmaf(-(f), p0.z, (A).z); (A).w = fmaf(-(f), p0.w, (A).w); \
    (B).x = fmaf(-(f), p1.x, (B).x); (B).y = fmaf(-(f), p1.y, (B).y); \
    (B).z = fmaf(-(f), p1.z, (B).z); (B).w = fmaf(-(f), p1.w, (B).w); \
    (C).x = fmaf(-(f), p2.x, (C).x); (C).y = fmaf(-(f), p2.y, (C).y); \
    (C).z = fmaf(-(f), p2.z, (C).z); (C).w = fmaf(-(f), p2.w, (C).w); }

template<int K>
__device__ __forceinline__ void rgj3_step(
    float4& a0, float4& b0, float4& c0,
    float4& a1, float4& b1, float4& c1,
    float4& a2, float4& b2, float4& c2,
    float* piv, int t) {
  constexpr int SET = K >> 2, OWN = K & 3;
  if (t == OWN) {
    if constexpr (SET == 0)      pivot_pub<K>(a0, b0, c0, piv);
    else if constexpr (SET == 1) pivot_pub<K>(a1, b1, c1, piv);
    else                         pivot_pub<K>(a2, b2, c2, piv);
  }
  WFENCE();
  const float4* pv = (const float4*)piv;
  float4 p0 = pv[0], p1 = pv[1], p2 = pv[2];
  {
    const bool own = (SET == 0) && (t == OWN);
    float cur = getel<K>(a0, b0, c0);
    float f = own ? 0.0f : cur;
    setel<K>(a0, b0, c0, own ? cur : 0.0f);
    ELIM(f, a0, b0, c0);
  }
  {
    const bool own = (SET == 1) && (t == OWN);
    float cur = getel<K>(a1, b1, c1);
    float f = own ? 0.0f : cur;
    setel<K>(a1, b1, c1, own ? cur : 0.0f);
    ELIM(f, a1, b1, c1);
  }
  {
    const bool own = (SET == 2) && (t == OWN);
    float cur = getel<K>(a2, b2, c2);
    float f = own ? 0.0f : cur;
    setel<K>(a2, b2, c2, own ? cur : 0.0f);
    ELIM(f, a2, b2, c2);
  }
  WFENCE();
}

template<int K>
__device__ __forceinline__ void rgj3_all(
    float4& a0, float4& b0, float4& c0,
    float4& a1, float4& b1, float4& c1,
    float4& a2, float4& b2, float4& c2,
    float* piv, int t) {
  rgj3_step<K>(a0, b0, c0, a1, b1, c1, a2, b2, c2, piv, t);
  if constexpr (K < 11) rgj3_all<K + 1>(a0, b0, c0, a1, b1, c1, a2, b2, c2, piv, t);
}

// ---- Gram rows (HtH) for rows t, t+4, t+8 ---------------------------------
__device__ __forceinline__ void gram3(const float* myH, int t,
    float4& a0, float4& b0, float4& c0,
    float4& a1, float4& b1, float4& c1,
    float4& a2, float4& b2, float4& c2) {
  a0 = make_float4(0.f, 0.f, 0.f, 0.f);
  b0 = a0; c0 = a0; a1 = a0; b1 = a0; c1 = a0; a2 = a0; b2 = a0; c2 = a0;
#pragma unroll
  for (int k = 0; k < 24; ++k) {
    const float4* hk = (const float4*)(myH + k * 12);
    float4 h0 = hk[0], h1 = hk[1], h2 = hk[2];
    float f0 = myH[k * 12 + t];
    float f1 = myH[k * 12 + t + 4];
    float f2v = myH[k * 12 + t + 8];
    VFMA(a0, f0, h0);  VFMA(b0, f0, h1);  VFMA(c0, f0, h2);
    VFMA(a1, f1, h0);  VFMA(b1, f1, h1);  VFMA(c1, f1, h2);
    VFMA(a2, f2v, h0); VFMA(b2, f2v, h1); VFMA(c2, f2v, h2);
  }
}

// ---- W = Ginv * H[r,:] for 3 consecutive own rows (coeffs read from LDS) --
__device__ __forceinline__ void buildW(const float* myH, const float* gi, int r0,
                                       float4* Wa, float4* Wb, float4* Wc) {
  Wa[0] = make_float4(0.f, 0.f, 0.f, 0.f); Wa[1] = Wa[0]; Wa[2] = Wa[0];
  Wb[0] = Wa[0]; Wb[1] = Wa[0]; Wb[2] = Wa[0];
  Wc[0] = Wa[0]; Wc[1] = Wa[0]; Wc[2] = Wa[0];
#pragma unroll
  for (int c = 0; c < 12; ++c) {
    const float4* g4 = (const float4*)(gi + c * 12);
    float4 r0v = g4[0], r1v = g4[1], r2v = g4[2];
    float k0 = myH[(r0 + 0) * 12 + c];
    float k1 = myH[(r0 + 1) * 12 + c];
    float k2 = myH[(r0 + 2) * 12 + c];
    VFMA(Wa[0], k0, r0v); VFMA(Wa[1], k0, r1v); VFMA(Wa[2], k0, r2v);
    VFMA(Wb[0], k1, r0v); VFMA(Wb[1], k1, r1v); VFMA(Wb[2], k1, r2v);
    VFMA(Wc[0], k2, r0v); VFMA(Wc[1], k2, r1v); VFMA(Wc[2], k2, r2v);
  }
}

// ---- one permuted Fm slot for 3 rows (base..base+2 of the lane's 6) -------
// Fm[r][c] = delta - <H[c,:], W[:,r]>. Slot (m,k): column c = 6*(t^m)+k.
// Pair layout: P = 3m + k/2, half = k&1 — pair halves share the DPP control.
template<int m, int k, int base>
__device__ __forceinline__ void slot4(const float* myH, int t,
    const float4* Wa, const float4* Wb, const float4* Wc,
    f2* pA, f2* pB, f2* pC) {
  const int c = 6 * (t ^ m) + k;
  const float4* hc = (const float4*)(myH + c * 12);
  float4 h0 = hc[0], h1 = hc[1], h2 = hc[2];
  float d0 = 0.f, d1 = 0.f, d2 = 0.f;
  FMA4(d0, h0, Wa[0]); FMA4(d0, h1, Wa[1]); FMA4(d0, h2, Wa[2]);
  FMA4(d1, h0, Wb[0]); FMA4(d1, h1, Wb[1]); FMA4(d1, h2, Wb[2]);
  FMA4(d2, h0, Wc[0]); FMA4(d2, h1, Wc[1]); FMA4(d2, h2, Wc[2]);
  float v0 = ((m == 0 && k == base + 0) ? 1.0f : 0.0f) - d0;
  float v1 = ((m == 0 && k == base + 1) ? 1.0f : 0.0f) - d1;
  float v2 = ((m == 0 && k == base + 2) ? 1.0f : 0.0f) - d2;
  constexpr int P = 3 * m + (k >> 1);
  if constexpr ((k & 1) == 0) { pA[P].x = v0; pB[P].x = v1; pC[P].x = v2; }
  else                        { pA[P].y = v0; pB[P].y = v1; pC[P].y = v2; }
}

#define SLOTS(base, pA, pB, pC)                                   \
  slot4<0,0,base>(myH,t,Wa,Wb,Wc,pA,pB,pC);                       \
  slot4<0,1,base>(myH,t,Wa,Wb,Wc,pA,pB,pC);                       \
  slot4<0,2,base>(myH,t,Wa,Wb,Wc,pA,pB,pC);                       \
  slot4<0,3,base>(myH,t,Wa,Wb,Wc,pA,pB,pC);                       \
  slot4<0,4,base>(myH,t,Wa,Wb,Wc,pA,pB,pC);                       \
  slot4<0,5,base>(myH,t,Wa,Wb,Wc,pA,pB,pC);                       \
  slot4<1,0,base>(myH,t,Wa,Wb,Wc,pA,pB,pC);                       \
  slot4<1,1,base>(myH,t,Wa,Wb,Wc,pA,pB,pC);                       \
  slot4<1,2,base>(myH,t,Wa,Wb,Wc,pA,pB,pC);                       \
  slot4<1,3,base>(myH,t,Wa,Wb,Wc,pA,pB,pC);                       \
  slot4<1,4,base>(myH,t,Wa,Wb,Wc,pA,pB,pC);                       \
  slot4<1,5,base>(myH,t,Wa,Wb,Wc,pA,pB,pC);                       \
  slot4<2,0,base>(myH,t,Wa,Wb,Wc,pA,pB,pC);                       \
  slot4<2,1,base>(myH,t,Wa,Wb,Wc,pA,pB,pC);                       \
  slot4<2,2,base>(myH,t,Wa,Wb,Wc,pA,pB,pC);                       \
  slot4<2,3,base>(myH,t,Wa,Wb,Wc,pA,pB,pC);                       \
  slot4<2,4,base>(myH,t,Wa,Wb,Wc,pA,pB,pC);                       \
  slot4<2,5,base>(myH,t,Wa,Wb,Wc,pA,pB,pC);                       \
  slot4<3,0,base>(myH,t,Wa,Wb,Wc,pA,pB,pC);                       \
  slot4<3,1,base>(myH,t,Wa,Wb,Wc,pA,pB,pC);                       \
  slot4<3,2,base>(myH,t,Wa,Wb,Wc,pA,pB,pC);                       \
  slot4<3,3,base>(myH,t,Wa,Wb,Wc,pA,pB,pC);                       \
  slot4<3,4,base>(myH,t,Wa,Wb,Wc,pA,pB,pC);                       \
  slot4<3,5,base>(myH,t,Wa,Wb,Wc,pA,pB,pC);

__global__ __attribute__((amdgpu_flat_work_group_size(BLOCK, BLOCK),
                          amdgpu_waves_per_eu(1, 4)))
void pdhg_kernel(const float* __restrict__ P, const float* __restrict__ q,
                 const float* __restrict__ H, const float* __restrict__ b,
                 const float* __restrict__ cf, const int* __restrict__ itp,
                 float* __restrict__ out, int Btot) {
  __shared__ __align__(16) float sH[EPB * HS];
  __shared__ __align__(16) float sGi[EPB * GS];
  __shared__ __align__(16) float sB[EPB * SS];
  __shared__ __align__(16) float sAux[EPB * SS];

  const int tid  = threadIdx.x;
  const int wq   = tid >> 6;          // wave 0..1 — fully independent
  const int lane = tid & 63;
  const int g16  = lane >> 2;         // 4-lane group 0..15
  const int t    = lane & 3;
  const int e    = wq * 16 + g16;     // block-local env
  const int env  = blockIdx.x * EPB + e;
  const int envW0 = blockIdx.x * EPB + wq * 16;
  const int niter = itp[0];
  const int r6 = 6 * t;               // first of this lane's 6 iteration rows

  // ---- PER-WAVE float4 staging of this wave's 16 envs: H, P, q, b ----
  {
    const float4* gH = (const float4*)(H + (size_t)envW0 * 288);
#pragma unroll
    for (int rep = 0; rep < 18; ++rep) {          // 16 envs * 72 f4 = 1152
      int i = lane + rep * 64;
      int ee = i / 72, off = i - ee * 72;
      *(float4*)&sH[(wq * 16 + ee) * HS + off * 4] = gH[i];
    }
    const float4* gP = (const float4*)(P + (size_t)envW0 * 144);
#pragma unroll
    for (int rep = 0; rep < 9; ++rep) {           // 16 envs * 36 f4 = 576
      int i = lane + rep * 64;
      int ee = i / 36, off = i - ee * 36;
      *(float4*)&sGi[(wq * 16 + ee) * GS + off * 4] = gP[i];
    }
    const float4* gq = (const float4*)(q + (size_t)envW0 * 12);
    if (lane < 48) {                              // 16 envs * 3 f4
      int ee = lane / 3, off = lane - ee * 3;
      *(float4*)&sAux[(wq * 16 + ee) * SS + off * 4] = gq[lane];
    }
    const float4* gb = (const float4*)(b + (size_t)envW0 * 24);
    {                                             // 16 envs * 6 f4 = 96
      int i = lane;
      int ee = i / 6, off = i - ee * 6;
      *(float4*)&sB[(wq * 16 + ee) * SS + off * 4] = gb[i];
      if (lane < 32) {
        i = lane + 64;
        ee = i / 6; off = i - ee * 6;
        *(float4*)&sB[(wq * 16 + ee) * SS + off * 4] = gb[i];
      }
    }
  }
  WFENCE();

  const float* myH = &sH[e * HS];
  float* giB  = &sGi[e * GS];
  float* auxB = &sAux[e * SS];
  float* bBm  = &sB[e * SS];
  const float* bB = bBm;

  // ---- G = P + HtH in registers (rows t, t+4, t+8); invert in place -------
  float4 a0, b0, c0, a1, b1, c1, a2, b2, c2;
  gram3(myH, t, a0, b0, c0, a1, b1, c1, a2, b2, c2);
  {
    const float4* p0 = (const float4*)(giB + t * 12);
    const float4* p1 = (const float4*)(giB + (t + 4) * 12);
    const float4* p2 = (const float4*)(giB + (t + 8) * 12);
    float4 q0 = p0[0], q1 = p0[1], q2 = p0[2];
    float4 r0 = p1[0], r1 = p1[1], r2 = p1[2];
    float4 s0 = p2[0], s1 = p2[1], s2 = p2[2];
    ADD4(a0, q0); ADD4(b0, q1); ADD4(c0, q2);
    ADD4(a1, r0); ADD4(b1, r1); ADD4(c1, r2);
    ADD4(a2, s0); ADD4(b2, s1); ADD4(c2, s2);
  }
  rgj3_all<0>(a0, b0, c0, a1, b1, c1, a2, b2, c2, auxB + 12, t);

  // ---- publish Ginv to LDS (overwrites staged P) + y = Ginv*q -------------
  {
    float4* w0 = (float4*)(giB + t * 12);        w0[0] = a0; w0[1] = b0; w0[2] = c0;
    float4* w1 = (float4*)(giB + (t + 4) * 12);  w1[0] = a1; w1[1] = b1; w1[2] = c1;
    float4* w2 = (float4*)(giB + (t + 8) * 12);  w2[0] = a2; w2[1] = b2; w2[2] = c2;
  }
  float y0 = dot12(a0, b0, c0, auxB);
  float y1 = dot12(a1, b1, c1, auxB);
  float y2 = dot12(a2, b2, c2, auxB);
  WFENCE();
  auxB[12 + t] = y0; auxB[16 + t] = y1; auxB[20 + t] = y2;
  WFENCE();

  // ---- permuted Fm rows (6 rows x 12 col-pairs), two 3-row passes ---------
  f2 pm0_[12], pm1_[12], pm2_[12], pm3_[12], pm4_[12], pm5_[12];
  {
    float4 Wa[3], Wb[3], Wc[3];
    buildW(myH, giB, r6 + 0, Wa, Wb, Wc);
    SLOTS(0, pm0_, pm1_, pm2_)
    buildW(myH, giB, r6 + 3, Wa, Wb, Wc);
    SLOTS(3, pm3_, pm4_, pm5_)
  }

  // ---- u = H*y for the 6 own rows (short live range) ----------------------
  float u0, u1, u2, u3, u4, u5;
  {
    const float4* y4 = (const float4*)(auxB + 12);
    float4 ya = y4[0], yb = y4[1], yc = y4[2];
#define UROW(rr, dst) { const float4* hp = (const float4*)(myH + (r6 + (rr)) * 12); \
      float4 h0 = hp[0], h1 = hp[1], h2 = hp[2]; dst = 0.f;                         \
      FMA4(dst, h0, ya); FMA4(dst, h1, yb); FMA4(dst, h2, yc); }
    UROW(0, u0) UROW(1, u1) UROW(2, u2) UROW(3, u3) UROW(4, u4) UROW(5, u5)
#undef UROW
  }

  // ---- mu = H*y - Fm*b (b gathered in the same pair order) ----------------
  float mu0, mu1, mu2, mu3, mu4, mu5;
  {
    const int cA = 6 * (t ^ 1), cB = 6 * (t ^ 2), cC = 6 * (t ^ 3);
    f2 bq0 = { bB[r6 + 0], bB[r6 + 1] };
    f2 bq1 = { bB[r6 + 2], bB[r6 + 3] };
    f2 bq2 = { bB[r6 + 4], bB[r6 + 5] };
    f2 bq3 = { bB[cA + 0], bB[cA + 1] };
    f2 bq4 = { bB[cA + 2], bB[cA + 3] };
    f2 bq5 = { bB[cA + 4], bB[cA + 5] };
    f2 bq6 = { bB[cB + 0], bB[cB + 1] };
    f2 bq7 = { bB[cB + 2], bB[cB + 3] };
    f2 bq8 = { bB[cB + 4], bB[cB + 5] };
    f2 bq9 = { bB[cC + 0], bB[cC + 1] };
    f2 bq10 = { bB[cC + 2], bB[cC + 3] };
    f2 bq11 = { bB[cC + 4], bB[cC + 5] };
#define MUROW(rr, uu) {                                              \
    f2 S1 = {0.f, 0.f}, S2 = {0.f, 0.f};                             \
    S1 = pkfma(pm##rr##_[0], bq0, S1);                               \
    S1 = pkfma(pm##rr##_[1], bq1, S1);                               \
    S1 = pkfma(pm##rr##_[2], bq2, S1);                               \
    S1 = pkfma(pm##rr##_[3], bq3, S1);                               \
    S1 = pkfma(pm##rr##_[4], bq4, S1);                               \
    S1 = pkfma(pm##rr##_[5], bq5, S1);                               \
    S2 = pkfma(pm##rr##_[6], bq6, S2);                               \
    S2 = pkfma(pm##rr##_[7], bq7, S2);                               \
    S2 = pkfma(pm##rr##_[8], bq8, S2);                               \
    S2 = pkfma(pm##rr##_[9], bq9, S2);                               \
    S2 = pkfma(pm##rr##_[10], bq10, S2);                             \
    S2 = pkfma(pm##rr##_[11], bq11, S2);                             \
    f2 St = S1 + S2;                                                 \
    mu##rr = (uu) - (St.x + St.y); }
    MUROW(0, u0) MUROW(1, u1) MUROW(2, u2)
    MUROW(3, u3) MUROW(4, u4) MUROW(5, u5)
#undef MUROW
  }
  const float* cfp = cf + (size_t)env * 24 + r6;
  f2 cf0p = { cfp[0], cfp[1] };
  f2 cf1p = { cfp[2], cfp[3] };
  f2 cf2p = { cfp[4], cfp[5] };

  // ---- iterations: 18 depth-1 DPP + 72 pkfma + pk-paired tail -------------
  // Lane t<2: rows 0..11 = cones (two 3-row cones per lane, gate rows 2,5).
  // Lane t>=2: rows 12..23 = box (clamp +-10, gate always).
  const float plo  = (t < 2) ? -3.0e38f : -10.0f;
  const float phi  = (t < 2) ?  3.0e38f :  10.0f;
  const float pthr = (t < 2) ? 0.0f     : -3.0e38f;
  const f2 lo2 = { plo, plo };
  const f2 hi2 = { phi, phi };
  const f2 n2  = { -2.0f, -2.0f };
  f2 l0p = {0.f, 0.f}, l1p = l0p, l2p = l0p;
  f2 z0p = l0p, z1p = l0p, z2p = l0p;
#pragma unroll 1
  for (int it = 0; it < niter; ++it) {
    f2 q0 = l0p + z0p;                  // v_pk_add_f32 x3 (s pairs)
    f2 q1 = l1p + z1p;
    f2 q2 = l2p + z2p;
    // 18 DPPs, all depth-1, pair halves share the control (mov-free)
    f2 q3, q4, q5, q6, q7, q8, q9, q10, q11;
    q3.x = dppv<DPP_XOR1>(q0.x);  q3.y = dppv<DPP_XOR1>(q0.y);
    q4.x = dppv<DPP_XOR1>(q1.x);  q4.y = dppv<DPP_XOR1>(q1.y);
    q5.x = dppv<DPP_XOR1>(q2.x);  q5.y = dppv<DPP_XOR1>(q2.y);
    q6.x = dppv<DPP_XOR2>(q0.x);  q6.y = dppv<DPP_XOR2>(q0.y);
    q7.x = dppv<DPP_XOR2>(q1.x);  q7.y = dppv<DPP_XOR2>(q1.y);
    q8.x = dppv<DPP_XOR2>(q2.x);  q8.y = dppv<DPP_XOR2>(q2.y);
    q9.x = dppv<DPP_QP3>(q0.x);   q9.y = dppv<DPP_QP3>(q0.y);
    q10.x = dppv<DPP_QP3>(q1.x);  q10.y = dppv<DPP_QP3>(q1.y);
    q11.x = dppv<DPP_QP3>(q2.x);  q11.y = dppv<DPP_QP3>(q2.y);
    // 72 pkfma: per row two independent 6-chains
#define FMAROW(rr, wdst) {                                           \
    f2 A = { mu##rr, 0.f };                                          \
    f2 Bv = { 0.f, 0.f };                                            \
    A = pkfma(pm##rr##_[0], q0, A);                                  \
    A = pkfma(pm##rr##_[1], q1, A);                                  \
    A = pkfma(pm##rr##_[2], q2, A);                                  \
    A = pkfma(pm##rr##_[3], q3, A);                                  \
    A = pkfma(pm##rr##_[4], q4, A);                                  \
    A = pkfma(pm##rr##_[5], q5, A);                                  \
    Bv = pkfma(pm##rr##_[6], q6, Bv);                                \
    Bv = pkfma(pm##rr##_[7], q7, Bv);                                \
    Bv = pkfma(pm##rr##_[8], q8, Bv);                                \
    Bv = pkfma(pm##rr##_[9], q9, Bv);                                \
    Bv = pkfma(pm##rr##_[10], q10, Bv);                              \
    Bv = pkfma(pm##rr##_[11], q11, Bv);                              \
    f2 C = A + Bv;                                                   \
    wdst = C.x + C.y; }
    f2 w0p, w1p, w2p;
    FMAROW(0, w0p.x) FMAROW(1, w0p.y)
    FMAROW(2, w1p.x) FMAROW(3, w1p.y)
    FMAROW(4, w2p.x) FMAROW(5, w2p.y)
#undef FMAROW
    // pk tail: zp = s - 2w; clamp; gate; scale
    f2 zp0 = pkfma(n2, w0p, q0);
    f2 zp1 = pkfma(n2, w1p, q1);
    f2 zp2 = pkfma(n2, w2p, q2);
    l0p = w0p; l1p = w1p; l2p = w2p;
    bool gA = zp1.x > pthr;             // row 2 gate (cone 0) / box: true
    bool gB = zp2.y > pthr;             // row 5 gate (cone 1) / box: true
    f2 c0p = __builtin_elementwise_min(__builtin_elementwise_max(zp0, lo2), hi2);
    f2 c1p = __builtin_elementwise_min(__builtin_elementwise_max(zp1, lo2), hi2);
    f2 c2p = __builtin_elementwise_min(__builtin_elementwise_max(zp2, lo2), hi2);
    f2 m0 = c0p * cf0p;                 // v_pk_mul_f32 x3
    f2 m1 = c1p * cf1p;
    f2 m2 = c2p * cf2p;
    z0p.x = gA ? m0.x : 0.0f;
    z0p.y = gA ? m0.y : 0.0f;
    z1p.x = gA ? m1.x : 0.0f;
    z1p.y = gB ? m1.y : 0.0f;           // row 3 -> cone 1 gate
    z2p.x = gB ? m2.x : 0.0f;
    z2p.y = gB ? m2.y : 0.0f;
  }

  // ---- outputs: lz, then x = (HtH)^-1 Ht (z - b) --------------------------
  float* xout  = out;
  float* lzout = out + (size_t)Btot * 12;
  {
    size_t base = (size_t)env * 48 + r6;
    lzout[base + 0] = l0p.x; lzout[base + 1] = l0p.y; lzout[base + 2] = l1p.x;
    lzout[base + 3] = l1p.y; lzout[base + 4] = l2p.x; lzout[base + 5] = l2p.y;
    lzout[base + 24 + 0] = z0p.x; lzout[base + 24 + 1] = z0p.y; lzout[base + 24 + 2] = z1p.x;
    lzout[base + 24 + 3] = z1p.y; lzout[base + 24 + 4] = z2p.x; lzout[base + 24 + 5] = z2p.y;
  }

  float bo0 = bB[r6 + 0], bo1 = bB[r6 + 1], bo2 = bB[r6 + 2];
  float bo3 = bB[r6 + 3], bo4 = bB[r6 + 4], bo5 = bB[r6 + 5];
  WFENCE();
  auxB[r6 + 0] = z0p.x - bo0; auxB[r6 + 1] = z0p.y - bo1; auxB[r6 + 2] = z1p.x - bo2;
  auxB[r6 + 3] = z1p.y - bo3; auxB[r6 + 4] = z2p.x - bo4; auxB[r6 + 5] = z2p.y - bo5;
  WFENCE();

  // rv = Ht (z - b), three owned columns in one pass
  float rv0 = 0.f, rv1 = 0.f, rv2 = 0.f;
  {
    const float4* a4 = (const float4*)auxB;
    float4 au0 = a4[0], au1 = a4[1], au2 = a4[2], au3 = a4[3], au4 = a4[4], au5 = a4[5];
#define RVS(k, AV) { rv0 = fmaf(myH[(k) * 12 + t],     (AV), rv0);  \
                     rv1 = fmaf(myH[(k) * 12 + t + 4], (AV), rv1);  \
                     rv2 = fmaf(myH[(k) * 12 + t + 8], (AV), rv2); }
    RVS(0,  au0.x) RVS(1,  au0.y) RVS(2,  au0.z) RVS(3,  au0.w)
    RVS(4,  au1.x) RVS(5,  au1.y) RVS(6,  au1.z) RVS(7,  au1.w)
    RVS(8,  au2.x) RVS(9,  au2.y) RVS(10, au2.z) RVS(11, au2.w)
    RVS(12, au3.x) RVS(13, au3.y) RVS(14, au3.z) RVS(15, au3.w)
    RVS(16, au4.x) RVS(17, au4.y) RVS(18, au4.z) RVS(19, au4.w)
    RVS(20, au5.x) RVS(21, au5.y) RVS(22, au5.z) RVS(23, au5.w)
#undef RVS
  }

  // second Gram (no P) + register GJ; pivot buffer reuses sB[0..11]
  gram3(myH, t, a0, b0, c0, a1, b1, c1, a2, b2, c2);
  WFENCE();
  auxB[t] = rv0; auxB[t + 4] = rv1; auxB[t + 8] = rv2;
  WFENCE();
  rgj3_all<0>(a0, b0, c0, a1, b1, c1, a2, b2, c2, bBm, t);

  xout[(size_t)env * 12 + t]     = dot12(a0, b0, c0, auxB);
  xout[(size_t)env * 12 + t + 4] = dot12(a1, b1, c1, auxB);
  xout[(size_t)env * 12 + t + 8] = dot12(a2, b2, c2, auxB);
}

extern "C" void kernel_launch(void* const* d_in, const int* in_sizes, int n_in,
                              void* d_out, int out_size, void* d_ws, size_t ws_size,
                              hipStream_t stream) {
  const float* P  = (const float*)d_in[0];
  const float* q  = (const float*)d_in[1];
  const float* H  = (const float*)d_in[2];
  const float* b  = (const float*)d_in[3];
  const float* cf = (const float*)d_in[4];
  const int*   it = (const int*)d_in[5];
  float* out = (float*)d_out;
  const int B = in_sizes[1] / 12;       // q is [B,12]
  const int grid = B / EPB;             // 16384/32 = 512 blocks
  pdhg_kernel<<<grid, BLOCK, 0, stream>>>(P, q, H, b, cf, it, out, B);
}

// Round 13
// 130.844 us; speedup vs baseline: 1.0082x; 1.0082x over previous
//
#include <hip/hip_runtime.h>

#define EPB 32          // envs per block (16 per wave, 4 lanes per env)
#define BLOCK 128       // 2 waves per block; 1 wave/SIMD at 2 blocks/CU
#define HS 292          // H LDS stride (288 + 4)
#define GS 148          // G/Ginv LDS stride (144 + 4)
#define SS 28           // b / aux stride (24 + 4)

#define WFENCE() __builtin_amdgcn_wave_barrier()   // compiler fence, 0 instr

#define DPP_XOR1 0xB1   // quad_perm [1,0,3,2]  : lane ^= 1
#define DPP_XOR2 0x4E   // quad_perm [2,3,0,1]  : lane ^= 2
#define DPP_QP3  0x1B   // quad_perm [3,2,1,0]  : lane ^= 3

typedef float f2 __attribute__((ext_vector_type(2)));

__device__ __forceinline__ f2 pkfma(f2 a, f2 b, f2 c) {
  return __builtin_elementwise_fma(a, b, c);   // -> v_pk_fma_f32 on gfx950
}

// acc += dot(f4, s4)
#define FMA4(acc, f, s)                                         \
  acc = fmaf((f).x, (s).x,                                      \
        fmaf((f).y, (s).y,                                      \
        fmaf((f).z, (s).z,                                      \
        fmaf((f).w, (s).w, (acc)))))

// acc4 += s * v4
#define VFMA(acc, s, v)                                         \
  { (acc).x = fmaf((s), (v).x, (acc).x);                        \
    (acc).y = fmaf((s), (v).y, (acc).y);                        \
    (acc).z = fmaf((s), (v).z, (acc).z);                        \
    (acc).w = fmaf((s), (v).w, (acc).w); }

#define ADD4(A, B) { (A).x += (B).x; (A).y += (B).y; (A).z += (B).z; (A).w += (B).w; }

template<int CTRL>
__device__ __forceinline__ float dppv(float v) {
  return __int_as_float(__builtin_amdgcn_update_dpp(
      0, __float_as_int(v), CTRL, 0xF, 0xF, true));
}

template<int K>
__device__ __forceinline__ float getel(const float4& a, const float4& b, const float4& c) {
  if constexpr (K == 0) return a.x; else if constexpr (K == 1) return a.y;
  else if constexpr (K == 2) return a.z; else if constexpr (K == 3) return a.w;
  else if constexpr (K == 4) return b.x; else if constexpr (K == 5) return b.y;
  else if constexpr (K == 6) return b.z; else if constexpr (K == 7) return b.w;
  else if constexpr (K == 8) return c.x; else if constexpr (K == 9) return c.y;
  else if constexpr (K == 10) return c.z; else return c.w;
}
template<int K>
__device__ __forceinline__ void setel(float4& a, float4& b, float4& c, float v) {
  if constexpr (K == 0) a.x = v; else if constexpr (K == 1) a.y = v;
  else if constexpr (K == 2) a.z = v; else if constexpr (K == 3) a.w = v;
  else if constexpr (K == 4) b.x = v; else if constexpr (K == 5) b.y = v;
  else if constexpr (K == 6) b.z = v; else if constexpr (K == 7) b.w = v;
  else if constexpr (K == 8) c.x = v; else if constexpr (K == 9) c.y = v;
  else if constexpr (K == 10) c.z = v; else c.w = v;
}

__device__ __forceinline__ float dot12(float4 a0, float4 a1, float4 a2,
                                       const float* p) {
  const float4* p4 = (const float4*)p;
  float4 b0 = p4[0], b1 = p4[1], b2 = p4[2];
  float acc = 0.f;
  FMA4(acc, a0, b0); FMA4(acc, a1, b1); FMA4(acc, a2, b2);
  return acc;
}

// ---- register-resident Gauss-Jordan, 3 row-sets per lane ------------------
// Lane t (0..3) owns rows t (set0), t+4 (set1), t+8 (set2).
// Pivot row goes through LDS (r10 proven; r11's DPP-broadcast variant added
// ~600 issue-slots and regressed 9% at 1 wave/SIMD).
template<int K>
__device__ __forceinline__ void pivot_pub(float4& a, float4& b, float4& c, float* piv) {
  float ip = 1.0f / getel<K>(a, b, c);
  setel<K>(a, b, c, 1.0f);
  a.x *= ip; a.y *= ip; a.z *= ip; a.w *= ip;
  b.x *= ip; b.y *= ip; b.z *= ip; b.w *= ip;
  c.x *= ip; c.y *= ip; c.z *= ip; c.w *= ip;
  float4* pv = (float4*)piv;
  pv[0] = a; pv[1] = b; pv[2] = c;
}

#define ELIM(f, A, B, C)                                              \
  { (A).x = fmaf(-(f), p0.x, (A).x); (A).y = fmaf(-(f), p0.y, (A).y); \
    (A).z = fmaf(-(f), p0.z, (A).z); (A).w = fmaf(-(f), p0.w, (A).w); \
    (B).x = fmaf(-(f), p1.x, (B).x); (B).y = fmaf(-(f), p1.y, (B).y); \
    (B).z = fmaf(-(f), p1.z, (B).z); (B).w = fmaf(-(f), p1.w, (B).w); \
    (C).x = fmaf(-(f), p2.x, (C).x); (C).y = fmaf(-(f), p2.y, (C).y); \
    (C).z = fmaf(-(f), p2.z, (C).z); (C).w = fmaf(-(f), p2.w, (C).w); }

template<int K>
__device__ __forceinline__ void rgj3_step(
    float4& a0, float4& b0, float4& c0,
    float4& a1, float4& b1, float4& c1,
    float4& a2, float4& b2, float4& c2,
    float* piv, int t) {
  constexpr int SET = K >> 2, OWN = K & 3;
  if (t == OWN) {
    if constexpr (SET == 0)      pivot_pub<K>(a0, b0, c0, piv);
    else if constexpr (SET == 1) pivot_pub<K>(a1, b1, c1, piv);
    else                         pivot_pub<K>(a2, b2, c2, piv);
  }
  WFENCE();
  const float4* pv = (const float4*)piv;
  float4 p0 = pv[0], p1 = pv[1], p2 = pv[2];
  {
    const bool own = (SET == 0) && (t == OWN);
    float cur = getel<K>(a0, b0, c0);
    float f = own ? 0.0f : cur;
    setel<K>(a0, b0, c0, own ? cur : 0.0f);
    ELIM(f, a0, b0, c0);
  }
  {
    const bool own = (SET == 1) && (t == OWN);
    float cur = getel<K>(a1, b1, c1);
    float f = own ? 0.0f : cur;
    setel<K>(a1, b1, c1, own ? cur : 0.0f);
    ELIM(f, a1, b1, c1);
  }
  {
    const bool own = (SET == 2) && (t == OWN);
    float cur = getel<K>(a2, b2, c2);
    float f = own ? 0.0f : cur;
    setel<K>(a2, b2, c2, own ? cur : 0.0f);
    ELIM(f, a2, b2, c2);
  }
  WFENCE();
}

template<int K>
__device__ __forceinline__ void rgj3_all(
    float4& a0, float4& b0, float4& c0,
    float4& a1, float4& b1, float4& c1,
    float4& a2, float4& b2, float4& c2,
    float* piv, int t) {
  rgj3_step<K>(a0, b0, c0, a1, b1, c1, a2, b2, c2, piv, t);
  if constexpr (K < 11) rgj3_all<K + 1>(a0, b0, c0, a1, b1, c1, a2, b2, c2, piv, t);
}

// ---- Gram rows (HtH) for rows t, t+4, t+8 ---------------------------------
__device__ __forceinline__ void gram3(const float* myH, int t,
    float4& a0, float4& b0, float4& c0,
    float4& a1, float4& b1, float4& c1,
    float4& a2, float4& b2, float4& c2) {
  a0 = make_float4(0.f, 0.f, 0.f, 0.f);
  b0 = a0; c0 = a0; a1 = a0; b1 = a0; c1 = a0; a2 = a0; b2 = a0; c2 = a0;
#pragma unroll
  for (int k = 0; k < 24; ++k) {
    const float4* hk = (const float4*)(myH + k * 12);
    float4 h0 = hk[0], h1 = hk[1], h2 = hk[2];
    float f0 = myH[k * 12 + t];
    float f1 = myH[k * 12 + t + 4];
    float f2v = myH[k * 12 + t + 8];
    VFMA(a0, f0, h0);  VFMA(b0, f0, h1);  VFMA(c0, f0, h2);
    VFMA(a1, f1, h0);  VFMA(b1, f1, h1);  VFMA(c1, f1, h2);
    VFMA(a2, f2v, h0); VFMA(b2, f2v, h1); VFMA(c2, f2v, h2);
  }
}

// ---- W = Ginv * H[r,:] for 3 consecutive own rows (coeffs read from LDS) --
__device__ __forceinline__ void buildW(const float* myH, const float* gi, int r0,
                                       float4* Wa, float4* Wb, float4* Wc) {
  Wa[0] = make_float4(0.f, 0.f, 0.f, 0.f); Wa[1] = Wa[0]; Wa[2] = Wa[0];
  Wb[0] = Wa[0]; Wb[1] = Wa[0]; Wb[2] = Wa[0];
  Wc[0] = Wa[0]; Wc[1] = Wa[0]; Wc[2] = Wa[0];
#pragma unroll
  for (int c = 0; c < 12; ++c) {
    const float4* g4 = (const float4*)(gi + c * 12);
    float4 r0v = g4[0], r1v = g4[1], r2v = g4[2];
    float k0 = myH[(r0 + 0) * 12 + c];
    float k1 = myH[(r0 + 1) * 12 + c];
    float k2 = myH[(r0 + 2) * 12 + c];
    VFMA(Wa[0], k0, r0v); VFMA(Wa[1], k0, r1v); VFMA(Wa[2], k0, r2v);
    VFMA(Wb[0], k1, r0v); VFMA(Wb[1], k1, r1v); VFMA(Wb[2], k1, r2v);
    VFMA(Wc[0], k2, r0v); VFMA(Wc[1], k2, r1v); VFMA(Wc[2], k2, r2v);
  }
}

// ---- one permuted Fm slot for 3 rows (base..base+2 of the lane's 6) -------
// Fm[r][c] = delta - <H[c,:], W[:,r]>. Slot (m,k): column c = 6*(t^m)+k.
// Pair layout: P = 3m + k/2, half = k&1 — pair halves share the DPP control.
template<int m, int k, int base>
__device__ __forceinline__ void slot4(const float* myH, int t,
    const float4* Wa, const float4* Wb, const float4* Wc,
    f2* pA, f2* pB, f2* pC) {
  const int c = 6 * (t ^ m) + k;
  const float4* hc = (const float4*)(myH + c * 12);
  float4 h0 = hc[0], h1 = hc[1], h2 = hc[2];
  float d0 = 0.f, d1 = 0.f, d2 = 0.f;
  FMA4(d0, h0, Wa[0]); FMA4(d0, h1, Wa[1]); FMA4(d0, h2, Wa[2]);
  FMA4(d1, h0, Wb[0]); FMA4(d1, h1, Wb[1]); FMA4(d1, h2, Wb[2]);
  FMA4(d2, h0, Wc[0]); FMA4(d2, h1, Wc[1]); FMA4(d2, h2, Wc[2]);
  float v0 = ((m == 0 && k == base + 0) ? 1.0f : 0.0f) - d0;
  float v1 = ((m == 0 && k == base + 1) ? 1.0f : 0.0f) - d1;
  float v2 = ((m == 0 && k == base + 2) ? 1.0f : 0.0f) - d2;
  constexpr int P = 3 * m + (k >> 1);
  if constexpr ((k & 1) == 0) { pA[P].x = v0; pB[P].x = v1; pC[P].x = v2; }
  else                        { pA[P].y = v0; pB[P].y = v1; pC[P].y = v2; }
}

#define SLOTS(base, pA, pB, pC)                                   \
  slot4<0,0,base>(myH,t,Wa,Wb,Wc,pA,pB,pC);                       \
  slot4<0,1,base>(myH,t,Wa,Wb,Wc,pA,pB,pC);                       \
  slot4<0,2,base>(myH,t,Wa,Wb,Wc,pA,pB,pC);                       \
  slot4<0,3,base>(myH,t,Wa,Wb,Wc,pA,pB,pC);                       \
  slot4<0,4,base>(myH,t,Wa,Wb,Wc,pA,pB,pC);                       \
  slot4<0,5,base>(myH,t,Wa,Wb,Wc,pA,pB,pC);                       \
  slot4<1,0,base>(myH,t,Wa,Wb,Wc,pA,pB,pC);                       \
  slot4<1,1,base>(myH,t,Wa,Wb,Wc,pA,pB,pC);                       \
  slot4<1,2,base>(myH,t,Wa,Wb,Wc,pA,pB,pC);                       \
  slot4<1,3,base>(myH,t,Wa,Wb,Wc,pA,pB,pC);                       \
  slot4<1,4,base>(myH,t,Wa,Wb,Wc,pA,pB,pC);                       \
  slot4<1,5,base>(myH,t,Wa,Wb,Wc,pA,pB,pC);                       \
  slot4<2,0,base>(myH,t,Wa,Wb,Wc,pA,pB,pC);                       \
  slot4<2,1,base>(myH,t,Wa,Wb,Wc,pA,pB,pC);                       \
  slot4<2,2,base>(myH,t,Wa,Wb,Wc,pA,pB,pC);                       \
  slot4<2,3,base>(myH,t,Wa,Wb,Wc,pA,pB,pC);                       \
  slot4<2,4,base>(myH,t,Wa,Wb,Wc,pA,pB,pC);                       \
  slot4<2,5,base>(myH,t,Wa,Wb,Wc,pA,pB,pC);                       \
  slot4<3,0,base>(myH,t,Wa,Wb,Wc,pA,pB,pC);                       \
  slot4<3,1,base>(myH,t,Wa,Wb,Wc,pA,pB,pC);                       \
  slot4<3,2,base>(myH,t,Wa,Wb,Wc,pA,pB,pC);                       \
  slot4<3,3,base>(myH,t,Wa,Wb,Wc,pA,pB,pC);                       \
  slot4<3,4,base>(myH,t,Wa,Wb,Wc,pA,pB,pC);                       \
  slot4<3,5,base>(myH,t,Wa,Wb,Wc,pA,pB,pC);

__global__ __attribute__((amdgpu_flat_work_group_size(BLOCK, BLOCK),
                          amdgpu_waves_per_eu(1, 4)))
void pdhg_kernel(const float* __restrict__ P, const float* __restrict__ q,
                 const float* __restrict__ H, const float* __restrict__ b,
                 const float* __restrict__ cf, const int* __restrict__ itp,
                 float* __restrict__ out, int Btot) {
  __shared__ __align__(16) float sH[EPB * HS];
  __shared__ __align__(16) float sGi[EPB * GS];
  __shared__ __align__(16) float sB[EPB * SS];
  __shared__ __align__(16) float sAux[EPB * SS];

  const int tid  = threadIdx.x;
  const int wq   = tid >> 6;          // wave 0..1 — fully independent
  const int lane = tid & 63;
  const int g16  = lane >> 2;         // 4-lane group 0..15
  const int t    = lane & 3;
  const int e    = wq * 16 + g16;     // block-local env
  const int env  = blockIdx.x * EPB + e;
  const int envW0 = blockIdx.x * EPB + wq * 16;
  const int niter = itp[0];
  const int r6 = 6 * t;               // first of this lane's 6 iteration rows

  // ---- PER-WAVE float4 staging of this wave's 16 envs: H, P, q, b ----
  {
    const float4* gH = (const float4*)(H + (size_t)envW0 * 288);
#pragma unroll
    for (int rep = 0; rep < 18; ++rep) {          // 16 envs * 72 f4 = 1152
      int i = lane + rep * 64;
      int ee = i / 72, off = i - ee * 72;
      *(float4*)&sH[(wq * 16 + ee) * HS + off * 4] = gH[i];
    }
    const float4* gP = (const float4*)(P + (size_t)envW0 * 144);
#pragma unroll
    for (int rep = 0; rep < 9; ++rep) {           // 16 envs * 36 f4 = 576
      int i = lane + rep * 64;
      int ee = i / 36, off = i - ee * 36;
      *(float4*)&sGi[(wq * 16 + ee) * GS + off * 4] = gP[i];
    }
    const float4* gq = (const float4*)(q + (size_t)envW0 * 12);
    if (lane < 48) {                              // 16 envs * 3 f4
      int ee = lane / 3, off = lane - ee * 3;
      *(float4*)&sAux[(wq * 16 + ee) * SS + off * 4] = gq[lane];
    }
    const float4* gb = (const float4*)(b + (size_t)envW0 * 24);
    {                                             // 16 envs * 6 f4 = 96
      int i = lane;
      int ee = i / 6, off = i - ee * 6;
      *(float4*)&sB[(wq * 16 + ee) * SS + off * 4] = gb[i];
      if (lane < 32) {
        i = lane + 64;
        ee = i / 6; off = i - ee * 6;
        *(float4*)&sB[(wq * 16 + ee) * SS + off * 4] = gb[i];
      }
    }
  }
  WFENCE();

  const float* myH = &sH[e * HS];
  float* giB  = &sGi[e * GS];
  float* auxB = &sAux[e * SS];
  float* bBm  = &sB[e * SS];
  const float* bB = bBm;

  // ---- G = P + HtH in registers (rows t, t+4, t+8); invert in place -------
  float4 a0, b0, c0, a1, b1, c1, a2, b2, c2;
  gram3(myH, t, a0, b0, c0, a1, b1, c1, a2, b2, c2);
  {
    const float4* p0 = (const float4*)(giB + t * 12);
    const float4* p1 = (const float4*)(giB + (t + 4) * 12);
    const float4* p2 = (const float4*)(giB + (t + 8) * 12);
    float4 q0 = p0[0], q1 = p0[1], q2 = p0[2];
    float4 r0 = p1[0], r1 = p1[1], r2 = p1[2];
    float4 s0 = p2[0], s1 = p2[1], s2 = p2[2];
    ADD4(a0, q0); ADD4(b0, q1); ADD4(c0, q2);
    ADD4(a1, r0); ADD4(b1, r1); ADD4(c1, r2);
    ADD4(a2, s0); ADD4(b2, s1); ADD4(c2, s2);
  }
  rgj3_all<0>(a0, b0, c0, a1, b1, c1, a2, b2, c2, auxB + 12, t);

  // ---- publish Ginv to LDS (overwrites staged P) + y = Ginv*q -------------
  {
    float4* w0 = (float4*)(giB + t * 12);        w0[0] = a0; w0[1] = b0; w0[2] = c0;
    float4* w1 = (float4*)(giB + (t + 4) * 12);  w1[0] = a1; w1[1] = b1; w1[2] = c1;
    float4* w2 = (float4*)(giB + (t + 8) * 12);  w2[0] = a2; w2[1] = b2; w2[2] = c2;
  }
  float y0 = dot12(a0, b0, c0, auxB);
  float y1 = dot12(a1, b1, c1, auxB);
  float y2 = dot12(a2, b2, c2, auxB);
  WFENCE();
  auxB[12 + t] = y0; auxB[16 + t] = y1; auxB[20 + t] = y2;
  WFENCE();

  // ---- permuted Fm rows (6 rows x 12 col-pairs), two 3-row passes ---------
  f2 pm0_[12], pm1_[12], pm2_[12], pm3_[12], pm4_[12], pm5_[12];
  {
    float4 Wa[3], Wb[3], Wc[3];
    buildW(myH, giB, r6 + 0, Wa, Wb, Wc);
    SLOTS(0, pm0_, pm1_, pm2_)
    buildW(myH, giB, r6 + 3, Wa, Wb, Wc);
    SLOTS(3, pm3_, pm4_, pm5_)
  }

  // ---- u = H*y for the 6 own rows (AFTER pm build: short live range) ------
  float u0, u1, u2, u3, u4, u5;
  {
    const float4* y4 = (const float4*)(auxB + 12);
    float4 ya = y4[0], yb = y4[1], yc = y4[2];
#define UROW(rr, dst) { const float4* hp = (const float4*)(myH + (r6 + (rr)) * 12); \
      float4 h0 = hp[0], h1 = hp[1], h2 = hp[2]; dst = 0.f;                         \
      FMA4(dst, h0, ya); FMA4(dst, h1, yb); FMA4(dst, h2, yc); }
    UROW(0, u0) UROW(1, u1) UROW(2, u2) UROW(3, u3) UROW(4, u4) UROW(5, u5)
#undef UROW
  }

  // ---- mu = H*y - Fm*b (b gathered in the same pair order) ----------------
  float mu0, mu1, mu2, mu3, mu4, mu5;
  {
    const int cA = 6 * (t ^ 1), cB = 6 * (t ^ 2), cC = 6 * (t ^ 3);
    f2 bq0 = { bB[r6 + 0], bB[r6 + 1] };
    f2 bq1 = { bB[r6 + 2], bB[r6 + 3] };
    f2 bq2 = { bB[r6 + 4], bB[r6 + 5] };
    f2 bq3 = { bB[cA + 0], bB[cA + 1] };
    f2 bq4 = { bB[cA + 2], bB[cA + 3] };
    f2 bq5 = { bB[cA + 4], bB[cA + 5] };
    f2 bq6 = { bB[cB + 0], bB[cB + 1] };
    f2 bq7 = { bB[cB + 2], bB[cB + 3] };
    f2 bq8 = { bB[cB + 4], bB[cB + 5] };
    f2 bq9 = { bB[cC + 0], bB[cC + 1] };
    f2 bq10 = { bB[cC + 2], bB[cC + 3] };
    f2 bq11 = { bB[cC + 4], bB[cC + 5] };
#define MUROW(rr, uu) {                                              \
    f2 S1 = {0.f, 0.f}, S2 = {0.f, 0.f};                             \
    S1 = pkfma(pm##rr##_[0], bq0, S1);                               \
    S1 = pkfma(pm##rr##_[1], bq1, S1);                               \
    S1 = pkfma(pm##rr##_[2], bq2, S1);                               \
    S1 = pkfma(pm##rr##_[3], bq3, S1);                               \
    S1 = pkfma(pm##rr##_[4], bq4, S1);                               \
    S1 = pkfma(pm##rr##_[5], bq5, S1);                               \
    S2 = pkfma(pm##rr##_[6], bq6, S2);                               \
    S2 = pkfma(pm##rr##_[7], bq7, S2);                               \
    S2 = pkfma(pm##rr##_[8], bq8, S2);                               \
    S2 = pkfma(pm##rr##_[9], bq9, S2);                               \
    S2 = pkfma(pm##rr##_[10], bq10, S2);                             \
    S2 = pkfma(pm##rr##_[11], bq11, S2);                             \
    f2 St = S1 + S2;                                                 \
    mu##rr = (uu) - (St.x + St.y); }
    MUROW(0, u0) MUROW(1, u1) MUROW(2, u2)
    MUROW(3, u3) MUROW(4, u4) MUROW(5, u5)
#undef MUROW
  }
  const float* cfp = cf + (size_t)env * 24 + r6;
  float cfv0 = cfp[0], cfv1 = cfp[1], cfv2 = cfp[2];
  float cfv3 = cfp[3], cfv4 = cfp[4], cfv5 = cfp[5];

  // ---- iterations: 18 depth-1 DPP + 72 pkfma (6 rows x 12 pairs) ----------
  // Lane t<2: rows 0..11 = cones (two 3-row cones per lane, gate rows 2,5).
  // Lane t>=2: rows 12..23 = box (clamp +-10, gate always).
  const float plo  = (t < 2) ? -3.0e38f : -10.0f;
  const float phi  = (t < 2) ?  3.0e38f :  10.0f;
  const float pthr = (t < 2) ? 0.0f     : -3.0e38f;
  float l0 = 0.f, l1 = 0.f, l2 = 0.f, l3 = 0.f, l4 = 0.f, l5 = 0.f;
  float z0 = 0.f, z1 = 0.f, z2 = 0.f, z3 = 0.f, z4 = 0.f, z5 = 0.f;
#pragma unroll 1
  for (int it = 0; it < niter; ++it) {
    f2 q0, q1, q2;                       // own s pairs (pair indices 0..2)
    q0.x = l0 + z0; q0.y = l1 + z1;
    q1.x = l2 + z2; q1.y = l3 + z3;
    q2.x = l4 + z4; q2.y = l5 + z5;
    // 18 DPPs, all depth-1, pair halves share the control (mov-free)
    f2 q3, q4, q5, q6, q7, q8, q9, q10, q11;
    q3.x = dppv<DPP_XOR1>(q0.x);  q3.y = dppv<DPP_XOR1>(q0.y);
    q4.x = dppv<DPP_XOR1>(q1.x);  q4.y = dppv<DPP_XOR1>(q1.y);
    q5.x = dppv<DPP_XOR1>(q2.x);  q5.y = dppv<DPP_XOR1>(q2.y);
    q6.x = dppv<DPP_XOR2>(q0.x);  q6.y = dppv<DPP_XOR2>(q0.y);
    q7.x = dppv<DPP_XOR2>(q1.x);  q7.y = dppv<DPP_XOR2>(q1.y);
    q8.x = dppv<DPP_XOR2>(q2.x);  q8.y = dppv<DPP_XOR2>(q2.y);
    q9.x = dppv<DPP_QP3>(q0.x);   q9.y = dppv<DPP_QP3>(q0.y);
    q10.x = dppv<DPP_QP3>(q1.x);  q10.y = dppv<DPP_QP3>(q1.y);
    q11.x = dppv<DPP_QP3>(q2.x);  q11.y = dppv<DPP_QP3>(q2.y);
    // 72 pkfma: per row two independent 6-chains
#define FMAROW(rr, wdst) {                                           \
    f2 A = { mu##rr, 0.f };                                          \
    f2 Bv = { 0.f, 0.f };                                            \
    A = pkfma(pm##rr##_[0], q0, A);                                  \
    A = pkfma(pm##rr##_[1], q1, A);                                  \
    A = pkfma(pm##rr##_[2], q2, A);                                  \
    A = pkfma(pm##rr##_[3], q3, A);                                  \
    A = pkfma(pm##rr##_[4], q4, A);                                  \
    A = pkfma(pm##rr##_[5], q5, A);                                  \
    Bv = pkfma(pm##rr##_[6], q6, Bv);                                \
    Bv = pkfma(pm##rr##_[7], q7, Bv);                                \
    Bv = pkfma(pm##rr##_[8], q8, Bv);                                \
    Bv = pkfma(pm##rr##_[9], q9, Bv);                                \
    Bv = pkfma(pm##rr##_[10], q10, Bv);                              \
    Bv = pkfma(pm##rr##_[11], q11, Bv);                              \
    f2 C = A + Bv;                                                   \
    wdst = C.x + C.y; }
    float w0, w1, w2, w3, w4, w5;
    FMAROW(0, w0) FMAROW(1, w1) FMAROW(2, w2)
    FMAROW(3, w3) FMAROW(4, w4) FMAROW(5, w5)
#undef FMAROW
    float zp0 = fmaf(-2.0f, w0, q0.x);
    float zp1 = fmaf(-2.0f, w1, q0.y);
    float zp2 = fmaf(-2.0f, w2, q1.x);
    float zp3 = fmaf(-2.0f, w3, q1.y);
    float zp4 = fmaf(-2.0f, w4, q2.x);
    float zp5 = fmaf(-2.0f, w5, q2.y);
    l0 = w0; l1 = w1; l2 = w2; l3 = w3; l4 = w4; l5 = w5;
    bool gA = zp2 > pthr;               // cone 0 gate (rows 0-2) / box: true
    bool gB = zp5 > pthr;               // cone 1 gate (rows 3-5) / box: true
    float e0 = gA ? cfv0 : 0.0f;
    float e1 = gA ? cfv1 : 0.0f;
    float e2 = gA ? cfv2 : 0.0f;
    float e3 = gB ? cfv3 : 0.0f;
    float e4 = gB ? cfv4 : 0.0f;
    float e5 = gB ? cfv5 : 0.0f;
    z0 = __builtin_amdgcn_fmed3f(zp0, plo, phi) * e0;
    z1 = __builtin_amdgcn_fmed3f(zp1, plo, phi) * e1;
    z2 = __builtin_amdgcn_fmed3f(zp2, plo, phi) * e2;
    z3 = __builtin_amdgcn_fmed3f(zp3, plo, phi) * e3;
    z4 = __builtin_amdgcn_fmed3f(zp4, plo, phi) * e4;
    z5 = __builtin_amdgcn_fmed3f(zp5, plo, phi) * e5;
  }

  // ---- outputs: lz, then x = (HtH)^-1 Ht (z - b) --------------------------
  float* xout  = out;
  float* lzout = out + (size_t)Btot * 12;
  {
    size_t base = (size_t)env * 48 + r6;
    lzout[base + 0] = l0; lzout[base + 1] = l1; lzout[base + 2] = l2;
    lzout[base + 3] = l3; lzout[base + 4] = l4; lzout[base + 5] = l5;
    lzout[base + 24 + 0] = z0; lzout[base + 24 + 1] = z1; lzout[base + 24 + 2] = z2;
    lzout[base + 24 + 3] = z3; lzout[base + 24 + 4] = z4; lzout[base + 24 + 5] = z5;
  }

  float bo0 = bB[r6 + 0], bo1 = bB[r6 + 1], bo2 = bB[r6 + 2];
  float bo3 = bB[r6 + 3], bo4 = bB[r6 + 4], bo5 = bB[r6 + 5];
  WFENCE();
  auxB[r6 + 0] = z0 - bo0; auxB[r6 + 1] = z1 - bo1; auxB[r6 + 2] = z2 - bo2;
  auxB[r6 + 3] = z3 - bo3; auxB[r6 + 4] = z4 - bo4; auxB[r6 + 5] = z5 - bo5;
  WFENCE();

  // rv = Ht (z - b), three owned columns in one pass
  float rv0 = 0.f, rv1 = 0.f, rv2 = 0.f;
  {
    const float4* a4 = (const float4*)auxB;
    float4 au0 = a4[0], au1 = a4[1], au2 = a4[2], au3 = a4[3], au4 = a4[4], au5 = a4[5];
#define RVS(k, AV) { rv0 = fmaf(myH[(k) * 12 + t],     (AV), rv0);  \
                     rv1 = fmaf(myH[(k) * 12 + t + 4], (AV), rv1);  \
                     rv2 = fmaf(myH[(k) * 12 + t + 8], (AV), rv2); }
    RVS(0,  au0.x) RVS(1,  au0.y) RVS(2,  au0.z) RVS(3,  au0.w)
    RVS(4,  au1.x) RVS(5,  au1.y) RVS(6,  au1.z) RVS(7,  au1.w)
    RVS(8,  au2.x) RVS(9,  au2.y) RVS(10, au2.z) RVS(11, au2.w)
    RVS(12, au3.x) RVS(13, au3.y) RVS(14, au3.z) RVS(15, au3.w)
    RVS(16, au4.x) RVS(17, au4.y) RVS(18, au4.z) RVS(19, au4.w)
    RVS(20, au5.x) RVS(21, au5.y) RVS(22, au5.z) RVS(23, au5.w)
#undef RVS
  }

  // second Gram (no P) + register GJ; pivot buffer reuses sB[0..11]
  gram3(myH, t, a0, b0, c0, a1, b1, c1, a2, b2, c2);
  WFENCE();
  auxB[t] = rv0; auxB[t + 4] = rv1; auxB[t + 8] = rv2;
  WFENCE();
  rgj3_all<0>(a0, b0, c0, a1, b1, c1, a2, b2, c2, bBm, t);

  xout[(size_t)env * 12 + t]     = dot12(a0, b0, c0, auxB);
  xout[(size_t)env * 12 + t + 4] = dot12(a1, b1, c1, auxB);
  xout[(size_t)env * 12 + t + 8] = dot12(a2, b2, c2, auxB);
}

extern "C" void kernel_launch(void* const* d_in, const int* in_sizes, int n_in,
                              void* d_out, int out_size, void* d_ws, size_t ws_size,
                              hipStream_t stream) {
  const float* P  = (const float*)d_in[0];
  const float* q  = (const float*)d_in[1];
  const float* H  = (const float*)d_in[2];
  const float* b  = (const float*)d_in[3];
  const float* cf = (const float*)d_in[4];
  const int*   it = (const int*)d_in[5];
  float* out = (float*)d_out;
  const int B = in_sizes[1] / 12;       // q is [B,12]
  const int grid = B / EPB;             // 16384/32 = 512 blocks
  pdhg_kernel<<<grid, BLOCK, 0, stream>>>(P, q, H, b, cf, it, out, B);
}